// Round 5
// baseline (261.021 us; speedup 1.0000x reference)
//
#include <hip/hip_runtime.h>
#include <hip/hip_cooperative_groups.h>

namespace cg = cooperative_groups;

typedef __bf16 bf16x8 __attribute__((ext_vector_type(8)));
typedef float f32x4 __attribute__((ext_vector_type(4)));

#define TWO_LOG2E 2.88539008177792681f   // 2*log2(e): exp(2x) = exp2(x*TWO_LOG2E)

#define GLOADLDS16(g, l) __builtin_amdgcn_global_load_lds(                     \
    (const __attribute__((address_space(1))) void*)(g),                        \
    (__attribute__((address_space(3))) void*)(l), 16, 0, 0)

__device__ __forceinline__ unsigned f2bf(float f) {
    unsigned u = __float_as_uint(f);
    return (u + 0x7FFFu + ((u >> 16) & 1u)) >> 16;   // RNE
}

// ================= phase 1: normalize z=[z1;z2] -> bf16 zn; zero S/out =================
__device__ __forceinline__ void phase1(const float* __restrict__ z1,
                                       const float* __restrict__ z2,
                                       unsigned short* __restrict__ zn,
                                       float* __restrict__ S,
                                       float* __restrict__ out) {
    const int tid = threadIdx.x, lane = tid & 63, wave = tid >> 6;
    for (int grp = blockIdx.x; grp < 512; grp += gridDim.x) {   // 16-row groups
        if (tid < 16) S[(grp << 4) + tid] = 0.f;
        if (grp == 0 && tid == 0) out[0] = 0.f;
#pragma unroll
        for (int r = 0; r < 4; ++r) {
            int row = (grp << 4) + (wave << 2) + r;
            const float* src = (row < 4096) ? (z1 + row * 256) : (z2 + (row - 4096) * 256);
            float4 v = ((const float4*)src)[lane];
            float ss = v.x * v.x + v.y * v.y + v.z * v.z + v.w * v.w;
#pragma unroll
            for (int m = 32; m > 0; m >>= 1) ss += __shfl_xor(ss, m, 64);
            float sc = 1.0f / fmaxf(sqrtf(ss), 1e-8f);
            uint2 w;
            w.x = f2bf(v.x * sc) | (f2bf(v.y * sc) << 16);
            w.y = f2bf(v.z * sc) | (f2bf(v.w * sc) << 16);
            *(uint2*)(zn + row * 256 + (lane << 2)) = w;
        }
    }
}

// ================= phase 2: triangular sim-exp, A in regs, B via 16KB LDS halves ========
// Tiles: strip i (128 rows at 128i), tile t (64 cols at 128i+64t), t in [0,128-2i),
// off_i = i*(129-i), total 4160. Block b of G owns [b*4160/G, (b+1)*4160/G).
// Per tile K=256 staged as two 16KB halves, double-buffered, one barrier per half;
// prefetch of half m+1 issued right after barrier(m) so barrier(m+1)'s vmcnt drain
// waits on compute-phase-old loads (never fresh).
__device__ __forceinline__ void phase2(const unsigned short* __restrict__ zn,
                                       float* __restrict__ S,
                                       unsigned short* __restrict__ Bs) {
    const int tid = threadIdx.x, lane = tid & 63, wave = tid >> 6;
    const int q = lane >> 4, n16 = lane & 15;
    const int wr = wave >> 1, wc = wave & 1;
    const int G = gridDim.x, b = blockIdx.x;

    const int gs = (b * 4160) / G;
    const int ge = ((b + 1) * 4160) / G;

    int si = 0;
    while ((si + 1) * (128 - si) <= gs) ++si;
    int ti = gs - si * (129 - si);

    // stage one 16KB half: 64 cols x 128 k-elems, chunk-swizzled (dest d = src ^ (c&15))
    auto stage = [&](int colBase, int h, int buf) {
        unsigned short* base = Bs + (buf << 13);
#pragma unroll
        for (int p = 0; p < 4; ++p) {
            int s16 = (p << 8) + tid;               // dest 16B slot 0..1023
            int c   = s16 >> 4;                     // col 0..63
            int k8  = (s16 & 15) ^ (c & 15);        // source chunk within half
            GLOADLDS16(zn + ((colBase + c) << 8) + (h << 7) + (k8 << 3),
                       base + (s16 << 3));
        }
    };

    bf16x8 a[4][8];                                 // wave's 64 rows x K=256
    auto loadA = [&](int rb) {
#pragma unroll
        for (int rt = 0; rt < 4; ++rt)
#pragma unroll
            for (int ks = 0; ks < 8; ++ks)
                a[rt][ks] = *(const bf16x8*)(zn + ((rb + (wr << 6) + (rt << 4) + n16) << 8)
                                                + (ks << 5) + (q << 3));
    };

    float rs[4][4];                                 // per-strip row-sum accumulators
#pragma unroll
    for (int i = 0; i < 4; ++i)
#pragma unroll
        for (int j = 0; j < 4; ++j) rs[i][j] = 0.f;

    auto flushRows = [&](int strip) {
        int base = (strip << 7) + (wr << 6) + (q << 2);
#pragma unroll
        for (int rt = 0; rt < 4; ++rt)
#pragma unroll
            for (int r = 0; r < 4; ++r) {
                float s = rs[rt][r];
                s += __shfl_xor(s, 1, 64);
                s += __shfl_xor(s, 2, 64);
                s += __shfl_xor(s, 4, 64);
                s += __shfl_xor(s, 8, 64);
                if (n16 == 0) atomicAdd(&S[base + (rt << 4) + r], s);
                rs[rt][r] = 0.f;
            }
    };

    loadA(si << 7);
    int curStrip = si;
    stage((si << 7) + (ti << 6), 0, 0);
    int pi = si, pt = ti, ph = 0;                   // walker = last staged (tile, half)
    int buf = 0;

    for (int g = gs; g < ge; ++g) {
        if (si != curStrip) { flushRows(curStrip); loadA(si << 7); curStrip = si; }
        const int rowBase = si << 7;
        const int colBase = rowBase + (ti << 6);

        f32x4 acc[4][2];
#pragma unroll
        for (int rt = 0; rt < 4; ++rt)
#pragma unroll
            for (int ct = 0; ct < 2; ++ct) acc[rt][ct] = (f32x4){0.f, 0.f, 0.f, 0.f};

#pragma unroll
        for (int h = 0; h < 2; ++h) {
            __syncthreads();                        // current buf staged (loads are old)
            // advance walker, prefetch next half into other buffer
            ph ^= 1;
            if (ph == 0) { ++pt; if (pt >= 128 - (pi << 1)) { ++pi; pt = 0; } }
            if (pi < 64) stage((pi << 7) + (pt << 6), ph, buf ^ 1);

            const unsigned short* bb = Bs + (buf << 13);
#pragma unroll
            for (int ksl = 0; ksl < 4; ++ksl) {
                bf16x8 bf[2];
#pragma unroll
                for (int ct = 0; ct < 2; ++ct) {
                    int c  = (wc << 5) + (ct << 4) + n16;
                    int k8 = ((ksl << 2) | q) ^ n16;
                    bf[ct] = *(const bf16x8*)(bb + (((c << 4) | k8) << 3));
                }
#pragma unroll
                for (int rt = 0; rt < 4; ++rt)
#pragma unroll
                    for (int ct = 0; ct < 2; ++ct)
                        acc[rt][ct] = __builtin_amdgcn_mfma_f32_16x16x32_bf16(
                            a[rt][(h << 2) + ksl], bf[ct], acc[rt][ct], 0, 0, 0);
            }
            buf ^= 1;
        }

        // epilogue: e = exp(2*dot); rows -> rs (strip-accumulated); cols -> atomics
        float cs[2] = {0.f, 0.f};
        const bool strad = (ti < 2);
        const int ibase = rowBase + (wr << 6) + (q << 2);
        const int jb    = colBase + (wc << 5) + n16;
#pragma unroll
        for (int rt = 0; rt < 4; ++rt)
#pragma unroll
            for (int ct = 0; ct < 2; ++ct)
#pragma unroll
                for (int r = 0; r < 4; ++r) {
                    float e = __builtin_amdgcn_exp2f(acc[rt][ct][r] * TWO_LOG2E);
                    if (strad) {
                        int ii = ibase + (rt << 4) + r;
                        int jj = jb + (ct << 4);
                        rs[rt][r] += (jj >= ii) ? e : 0.f;   // diagonal counted row-side
                        cs[ct]    += (jj >  ii) ? e : 0.f;
                    } else {
                        rs[rt][r] += e;
                        cs[ct]    += e;
                    }
                }
#pragma unroll
        for (int ct = 0; ct < 2; ++ct) {
            float s = cs[ct];
            s += __shfl_xor(s, 16, 64);
            s += __shfl_xor(s, 32, 64);
            if (q == 0) atomicAdd(&S[colBase + (wc << 5) + (ct << 4) + n16], s);
        }
        ++ti; if (ti >= 128 - (si << 1)) { ++si; ti = 0; }
    }
    flushRows(curStrip);
}

// ================= phase 3: loss = mean( log(S_i - e^{sim_ii}) - sim_{i,tar} ) ==========
__device__ __forceinline__ void phase3(const unsigned short* __restrict__ zn,
                                       const float* __restrict__ S,
                                       float* __restrict__ out,
                                       float* __restrict__ vals) {
    const int tid = threadIdx.x, lane = tid & 63, wave = tid >> 6;
    const int q = lane >> 4, n16 = lane & 15;
    const int rib = (wave << 2) + q;                // 0..15 rows per group
    for (int grp = blockIdx.x; grp < 512; grp += gridDim.x) {
        int row = (grp << 4) + rib;
        int tar = (row + 4096) & 8191;
        float drr = 0.f, drt = 0.f;
#pragma unroll
        for (int i = 0; i < 4; ++i) {
            int k = (i << 6) + (n16 << 2);
            uint2 ur = *(const uint2*)(zn + (row << 8) + k);
            uint2 ut = *(const uint2*)(zn + (tar << 8) + k);
            float a0 = __uint_as_float(ur.x << 16),  a1 = __uint_as_float(ur.x & 0xFFFF0000u);
            float a2 = __uint_as_float(ur.y << 16),  a3 = __uint_as_float(ur.y & 0xFFFF0000u);
            float b0 = __uint_as_float(ut.x << 16),  b1 = __uint_as_float(ut.x & 0xFFFF0000u);
            float b2 = __uint_as_float(ut.y << 16),  b3 = __uint_as_float(ut.y & 0xFFFF0000u);
            drr += a0 * a0 + a1 * a1 + a2 * a2 + a3 * a3;
            drt += a0 * b0 + a1 * b1 + a2 * b2 + a3 * b3;
        }
#pragma unroll
        for (int m = 1; m <= 8; m <<= 1) {
            drr += __shfl_xor(drr, m, 64);
            drt += __shfl_xor(drt, m, 64);
        }
        __syncthreads();
        if (n16 == 0) {
            float Sv = S[row] - __builtin_amdgcn_exp2f(drr * TWO_LOG2E);  // drop diagonal
            vals[rib] = 0.693147180559945f * __builtin_amdgcn_logf(Sv) - 2.0f * drt;
        }
        __syncthreads();
        if (tid == 0) {
            float s = 0.f;
#pragma unroll
            for (int i = 0; i < 16; ++i) s += vals[i];
            atomicAdd(out, s * (1.0f / 8192.0f));
        }
    }
}

// ================= kernels ==============================================================
__global__ void __launch_bounds__(256, 2) ntxent_fused(
    const float* __restrict__ z1, const float* __restrict__ z2,
    unsigned short* __restrict__ zn, float* __restrict__ S, float* __restrict__ out)
{
    __shared__ __align__(16) unsigned short Bs[2][8192];   // 2 x 16 KB
    phase1(z1, z2, zn, S, out);
    cg::this_grid().sync();
    phase2(zn, S, &Bs[0][0]);
    cg::this_grid().sync();
    phase3(zn, S, out, (float*)&Bs[0][0]);
}

__global__ void __launch_bounds__(256, 2) norm_k(
    const float* __restrict__ z1, const float* __restrict__ z2,
    unsigned short* __restrict__ zn, float* __restrict__ S, float* __restrict__ out)
{ phase1(z1, z2, zn, S, out); }

__global__ void __launch_bounds__(256, 2) simexp_k(
    const unsigned short* __restrict__ zn, float* __restrict__ S)
{
    __shared__ __align__(16) unsigned short Bs[2][8192];
    phase2(zn, S, &Bs[0][0]);
}

__global__ void __launch_bounds__(256, 2) finish_k(
    const unsigned short* __restrict__ zn, const float* __restrict__ S,
    float* __restrict__ out)
{
    __shared__ float vals[16];
    phase3(zn, S, out, vals);
}

extern "C" void kernel_launch(void* const* d_in, const int* in_sizes, int n_in,
                              void* d_out, int out_size, void* d_ws, size_t ws_size,
                              hipStream_t stream)
{
    const float* z1 = (const float*)d_in[0];
    const float* z2 = (const float*)d_in[1];
    unsigned short* zn = (unsigned short*)d_ws;                              // 4 MB
    float* S = (float*)((char*)d_ws + 8192 * 256 * sizeof(unsigned short));  // 32 KB
    float* out = (float*)d_out;

    // Host-only queries (graph-capture safe): pick cooperative grid size or fall back.
    int dev = 0;
    hipGetDevice(&dev);
    int coopOK = 0;
    hipDeviceGetAttribute(&coopOK, hipDeviceAttributeCooperativeLaunch, dev);
    int cus = 0;
    hipDeviceGetAttribute(&cus, hipDeviceAttributeMultiprocessorCount, dev);
    int maxB = 0;
    hipOccupancyMaxActiveBlocksPerMultiprocessor(&maxB, ntxent_fused, 256, 0);

    long long cap = (long long)maxB * (long long)cus;
    int G = (cap >= 512) ? 512 : (int)cap;

    if (coopOK && G >= 256) {
        void* args[] = {(void*)&z1, (void*)&z2, (void*)&zn, (void*)&S, (void*)&out};
        hipError_t err = hipLaunchCooperativeKernel(ntxent_fused, dim3(G), dim3(256),
                                                    args, 0, stream);
        if (err == hipSuccess) return;
    }
    // Fallback: same phases as separate (non-cooperative) kernels.
    norm_k<<<512, 256, 0, stream>>>(z1, z2, zn, S, out);
    simexp_k<<<512, 256, 0, stream>>>(zn, S);
    finish_k<<<512, 256, 0, stream>>>(zn, S, out);
}

// Round 6
// 143.582 us; speedup vs baseline: 1.8179x; 1.8179x over previous
//
#include <hip/hip_runtime.h>
#include <hip/hip_cooperative_groups.h>

namespace cg = cooperative_groups;

typedef __bf16 bf16x8 __attribute__((ext_vector_type(8)));
typedef float f32x4 __attribute__((ext_vector_type(4)));

#define TWO_LOG2E 2.88539008177792681f   // 2*log2(e): exp(2x) = exp2(x*TWO_LOG2E)

#define GLOADLDS16(g, l) __builtin_amdgcn_global_load_lds(                     \
    (const __attribute__((address_space(1))) void*)(g),                        \
    (__attribute__((address_space(3))) void*)(l), 16, 0, 0)

__device__ __forceinline__ unsigned f2bf(float f) {
    unsigned u = __float_as_uint(f);
    return (u + 0x7FFFu + ((u >> 16) & 1u)) >> 16;   // RNE
}

// ================= phase 1: normalize z=[z1;z2] -> bf16 zn; zero S/out =================
__device__ __forceinline__ void phase1(const float* __restrict__ z1,
                                       const float* __restrict__ z2,
                                       unsigned short* __restrict__ zn,
                                       float* __restrict__ S,
                                       float* __restrict__ out) {
    const int tid = threadIdx.x, lane = tid & 63, wave = tid >> 6;
    for (int grp = blockIdx.x; grp < 512; grp += gridDim.x) {   // 16-row groups
        if (tid < 16) S[(grp << 4) + tid] = 0.f;
        if (grp == 0 && tid == 0) out[0] = 0.f;
#pragma unroll
        for (int r = 0; r < 4; ++r) {
            int row = (grp << 4) + (wave << 2) + r;
            const float* src = (row < 4096) ? (z1 + row * 256) : (z2 + (row - 4096) * 256);
            float4 v = ((const float4*)src)[lane];
            float ss = v.x * v.x + v.y * v.y + v.z * v.z + v.w * v.w;
#pragma unroll
            for (int m = 32; m > 0; m >>= 1) ss += __shfl_xor(ss, m, 64);
            float sc = 1.0f / fmaxf(sqrtf(ss), 1e-8f);
            uint2 w;
            w.x = f2bf(v.x * sc) | (f2bf(v.y * sc) << 16);
            w.y = f2bf(v.z * sc) | (f2bf(v.w * sc) << 16);
            *(uint2*)(zn + row * 256 + (lane << 2)) = w;
        }
    }
}

// ================= phase 2: triangular sim-exp, A in regs, B via 16KB LDS halves ========
// Tiles: strip i (128 rows at 128i), tile t (64 cols at 128i+64t), t in [0,128-2i),
// off_i = i*(129-i), total 4160. Block b of G owns [b*4160/G, (b+1)*4160/G).
// Per tile K=256 staged as two 16KB halves, double-buffered, one barrier per half;
// prefetch of half m+1 issued right after barrier(m) so barrier(m+1)'s vmcnt drain
// waits on compute-phase-old loads (never fresh).
__device__ __forceinline__ void phase2(const unsigned short* __restrict__ zn,
                                       float* __restrict__ S,
                                       unsigned short* __restrict__ Bs) {
    const int tid = threadIdx.x, lane = tid & 63, wave = tid >> 6;
    const int q = lane >> 4, n16 = lane & 15;
    const int wr = wave >> 1, wc = wave & 1;
    const int G = gridDim.x, b = blockIdx.x;

    const int gs = (b * 4160) / G;
    const int ge = ((b + 1) * 4160) / G;

    int si = 0;
    while ((si + 1) * (128 - si) <= gs) ++si;
    int ti = gs - si * (129 - si);

    // stage one 16KB half: 64 cols x 128 k-elems, chunk-swizzled (dest d = src ^ (c&15))
    auto stage = [&](int colBase, int h, int buf) {
        unsigned short* base = Bs + (buf << 13);
#pragma unroll
        for (int p = 0; p < 4; ++p) {
            int s16 = (p << 8) + tid;               // dest 16B slot 0..1023
            int c   = s16 >> 4;                     // col 0..63
            int k8  = (s16 & 15) ^ (c & 15);        // source chunk within half
            GLOADLDS16(zn + ((colBase + c) << 8) + (h << 7) + (k8 << 3),
                       base + (s16 << 3));
        }
    };

    bf16x8 a[4][8];                                 // wave's 64 rows x K=256 (128 VGPRs)
    auto loadA = [&](int rb) {
#pragma unroll
        for (int rt = 0; rt < 4; ++rt)
#pragma unroll
            for (int ks = 0; ks < 8; ++ks)
                a[rt][ks] = *(const bf16x8*)(zn + ((rb + (wr << 6) + (rt << 4) + n16) << 8)
                                                + (ks << 5) + (q << 3));
    };

    float rs[4][4];                                 // per-strip row-sum accumulators
#pragma unroll
    for (int i = 0; i < 4; ++i)
#pragma unroll
        for (int j = 0; j < 4; ++j) rs[i][j] = 0.f;

    auto flushRows = [&](int strip) {
        int base = (strip << 7) + (wr << 6) + (q << 2);
#pragma unroll
        for (int rt = 0; rt < 4; ++rt)
#pragma unroll
            for (int r = 0; r < 4; ++r) {
                float s = rs[rt][r];
                s += __shfl_xor(s, 1, 64);
                s += __shfl_xor(s, 2, 64);
                s += __shfl_xor(s, 4, 64);
                s += __shfl_xor(s, 8, 64);
                if (n16 == 0) atomicAdd(&S[base + (rt << 4) + r], s);
                rs[rt][r] = 0.f;
            }
    };

    loadA(si << 7);
    int curStrip = si;
    stage((si << 7) + (ti << 6), 0, 0);
    int pi = si, pt = ti, ph = 0;                   // walker = last staged (tile, half)
    int buf = 0;

    for (int g = gs; g < ge; ++g) {
        if (si != curStrip) { flushRows(curStrip); loadA(si << 7); curStrip = si; }
        const int rowBase = si << 7;
        const int colBase = rowBase + (ti << 6);

        f32x4 acc[4][2];
#pragma unroll
        for (int rt = 0; rt < 4; ++rt)
#pragma unroll
            for (int ct = 0; ct < 2; ++ct) acc[rt][ct] = (f32x4){0.f, 0.f, 0.f, 0.f};

#pragma unroll
        for (int h = 0; h < 2; ++h) {
            __syncthreads();                        // current buf staged (loads are old)
            // advance walker, prefetch next half into other buffer
            ph ^= 1;
            if (ph == 0) { ++pt; if (pt >= 128 - (pi << 1)) { ++pi; pt = 0; } }
            if (pi < 64) stage((pi << 7) + (pt << 6), ph, buf ^ 1);

            const unsigned short* bb = Bs + (buf << 13);
#pragma unroll
            for (int ksl = 0; ksl < 4; ++ksl) {
                bf16x8 bf[2];
#pragma unroll
                for (int ct = 0; ct < 2; ++ct) {
                    int c  = (wc << 5) + (ct << 4) + n16;
                    int k8 = ((ksl << 2) | q) ^ n16;
                    bf[ct] = *(const bf16x8*)(bb + (((c << 4) | k8) << 3));
                }
#pragma unroll
                for (int rt = 0; rt < 4; ++rt)
#pragma unroll
                    for (int ct = 0; ct < 2; ++ct)
                        acc[rt][ct] = __builtin_amdgcn_mfma_f32_16x16x32_bf16(
                            a[rt][(h << 2) + ksl], bf[ct], acc[rt][ct], 0, 0, 0);
            }
            buf ^= 1;
        }

        // epilogue: e = exp(2*dot); rows -> rs (strip-accumulated); cols -> atomics
        float cs[2] = {0.f, 0.f};
        const bool strad = (ti < 2);
        const int ibase = rowBase + (wr << 6) + (q << 2);
        const int jb    = colBase + (wc << 5) + n16;
#pragma unroll
        for (int rt = 0; rt < 4; ++rt)
#pragma unroll
            for (int ct = 0; ct < 2; ++ct)
#pragma unroll
                for (int r = 0; r < 4; ++r) {
                    float e = __builtin_amdgcn_exp2f(acc[rt][ct][r] * TWO_LOG2E);
                    if (strad) {
                        int ii = ibase + (rt << 4) + r;
                        int jj = jb + (ct << 4);
                        rs[rt][r] += (jj >= ii) ? e : 0.f;   // diagonal counted row-side
                        cs[ct]    += (jj >  ii) ? e : 0.f;
                    } else {
                        rs[rt][r] += e;
                        cs[ct]    += e;
                    }
                }
#pragma unroll
        for (int ct = 0; ct < 2; ++ct) {
            float s = cs[ct];
            s += __shfl_xor(s, 16, 64);
            s += __shfl_xor(s, 32, 64);
            if (q == 0) atomicAdd(&S[colBase + (wc << 5) + (ct << 4) + n16], s);
        }
        ++ti; if (ti >= 128 - (si << 1)) { ++si; ti = 0; }
    }
    flushRows(curStrip);
}

// ================= phase 3: loss = mean( log(S_i - e^{sim_ii}) - sim_{i,tar} ) ==========
__device__ __forceinline__ void phase3(const unsigned short* __restrict__ zn,
                                       const float* __restrict__ S,
                                       float* __restrict__ out,
                                       float* __restrict__ vals) {
    const int tid = threadIdx.x, lane = tid & 63, wave = tid >> 6;
    const int q = lane >> 4, n16 = lane & 15;
    const int rib = (wave << 2) + q;                // 0..15 rows per group
    for (int grp = blockIdx.x; grp < 512; grp += gridDim.x) {
        int row = (grp << 4) + rib;
        int tar = (row + 4096) & 8191;
        float drr = 0.f, drt = 0.f;
#pragma unroll
        for (int i = 0; i < 4; ++i) {
            int k = (i << 6) + (n16 << 2);
            uint2 ur = *(const uint2*)(zn + (row << 8) + k);
            uint2 ut = *(const uint2*)(zn + (tar << 8) + k);
            float a0 = __uint_as_float(ur.x << 16),  a1 = __uint_as_float(ur.x & 0xFFFF0000u);
            float a2 = __uint_as_float(ur.y << 16),  a3 = __uint_as_float(ur.y & 0xFFFF0000u);
            float b0 = __uint_as_float(ut.x << 16),  b1 = __uint_as_float(ut.x & 0xFFFF0000u);
            float b2 = __uint_as_float(ut.y << 16),  b3 = __uint_as_float(ut.y & 0xFFFF0000u);
            drr += a0 * a0 + a1 * a1 + a2 * a2 + a3 * a3;
            drt += a0 * b0 + a1 * b1 + a2 * b2 + a3 * b3;
        }
#pragma unroll
        for (int m = 1; m <= 8; m <<= 1) {
            drr += __shfl_xor(drr, m, 64);
            drt += __shfl_xor(drt, m, 64);
        }
        __syncthreads();
        if (n16 == 0) {
            float Sv = S[row] - __builtin_amdgcn_exp2f(drr * TWO_LOG2E);  // drop diagonal
            vals[rib] = 0.693147180559945f * __builtin_amdgcn_logf(Sv) - 2.0f * drt;
        }
        __syncthreads();
        if (tid == 0) {
            float s = 0.f;
#pragma unroll
            for (int i = 0; i < 16; ++i) s += vals[i];
            atomicAdd(out, s * (1.0f / 8192.0f));
        }
    }
}

// ================= kernels ==============================================================
// (256,1): full 512-reg budget/wave. a[4][8]=128 VGPRs + working set ~ 230-260 total;
// (256,2)'s 256-reg cap split 128 arch/128 acc and spilled 200+ MB (R5 post-mortem).
__global__ void __launch_bounds__(256, 1) ntxent_fused(
    const float* __restrict__ z1, const float* __restrict__ z2,
    unsigned short* __restrict__ zn, float* __restrict__ S, float* __restrict__ out)
{
    __shared__ __align__(16) unsigned short Bs[2][8192];   // 2 x 16 KB
    phase1(z1, z2, zn, S, out);
    cg::this_grid().sync();
    phase2(zn, S, &Bs[0][0]);
    cg::this_grid().sync();
    phase3(zn, S, out, (float*)&Bs[0][0]);
}

__global__ void __launch_bounds__(256, 2) norm_k(
    const float* __restrict__ z1, const float* __restrict__ z2,
    unsigned short* __restrict__ zn, float* __restrict__ S, float* __restrict__ out)
{ phase1(z1, z2, zn, S, out); }

__global__ void __launch_bounds__(256, 1) simexp_k(
    const unsigned short* __restrict__ zn, float* __restrict__ S)
{
    __shared__ __align__(16) unsigned short Bs[2][8192];
    phase2(zn, S, &Bs[0][0]);
}

__global__ void __launch_bounds__(256, 2) finish_k(
    const unsigned short* __restrict__ zn, const float* __restrict__ S,
    float* __restrict__ out)
{
    __shared__ float vals[16];
    phase3(zn, S, out, vals);
}

extern "C" void kernel_launch(void* const* d_in, const int* in_sizes, int n_in,
                              void* d_out, int out_size, void* d_ws, size_t ws_size,
                              hipStream_t stream)
{
    const float* z1 = (const float*)d_in[0];
    const float* z2 = (const float*)d_in[1];
    unsigned short* zn = (unsigned short*)d_ws;                              // 4 MB
    float* S = (float*)((char*)d_ws + 8192 * 256 * sizeof(unsigned short));  // 32 KB
    float* out = (float*)d_out;

    // Host-only queries (graph-capture safe): pick cooperative grid size or fall back.
    int dev = 0;
    hipGetDevice(&dev);
    int coopOK = 0;
    hipDeviceGetAttribute(&coopOK, hipDeviceAttributeCooperativeLaunch, dev);
    int cus = 0;
    hipDeviceGetAttribute(&cus, hipDeviceAttributeMultiprocessorCount, dev);
    int maxB = 0;
    hipOccupancyMaxActiveBlocksPerMultiprocessor(&maxB, ntxent_fused, 256, 0);

    long long cap = (long long)maxB * (long long)cus;
    int G = (cap >= 512) ? 512 : (int)cap;

    if (coopOK && G >= 128) {
        void* args[] = {(void*)&z1, (void*)&z2, (void*)&zn, (void*)&S, (void*)&out};
        hipError_t err = hipLaunchCooperativeKernel(ntxent_fused, dim3(G), dim3(256),
                                                    args, 0, stream);
        if (err == hipSuccess) return;
    }
    // Fallback: same phases as separate (non-cooperative) kernels.
    norm_k<<<512, 256, 0, stream>>>(z1, z2, zn, S, out);
    simexp_k<<<512, 256, 0, stream>>>(zn, S);
    finish_k<<<512, 256, 0, stream>>>(zn, S, out);
}

// Round 7
// 122.426 us; speedup vs baseline: 2.1321x; 1.1728x over previous
//
#include <hip/hip_runtime.h>
#include <hip/hip_cooperative_groups.h>

namespace cg = cooperative_groups;

typedef __bf16 bf16x8 __attribute__((ext_vector_type(8)));
typedef float f32x4 __attribute__((ext_vector_type(4)));

#define TWO_LOG2E 2.88539008177792681f   // 2*log2(e): exp(2x) = exp2(x*TWO_LOG2E)

#define GLOADLDS16(g, l) __builtin_amdgcn_global_load_lds(                     \
    (const __attribute__((address_space(1))) void*)(g),                        \
    (__attribute__((address_space(3))) void*)(l), 16, 0, 0)

__device__ __forceinline__ unsigned f2bf(float f) {
    unsigned u = __float_as_uint(f);
    return (u + 0x7FFFu + ((u >> 16) & 1u)) >> 16;   // RNE
}

// ================= phase 1: normalize z=[z1;z2] -> bf16 zn; zero S/out =================
__device__ __forceinline__ void phase1(const float* __restrict__ z1,
                                       const float* __restrict__ z2,
                                       unsigned short* __restrict__ zn,
                                       float* __restrict__ S,
                                       float* __restrict__ out) {
    const int tid = threadIdx.x, lane = tid & 63, wave = tid >> 6;
    for (int grp = blockIdx.x; grp < 512; grp += gridDim.x) {   // 16-row groups
        if (tid < 16) S[(grp << 4) + tid] = 0.f;
        if (grp == 0 && tid == 0) out[0] = 0.f;
#pragma unroll
        for (int r = 0; r < 4; ++r) {
            int row = (grp << 4) + (wave << 2) + r;
            const float* src = (row < 4096) ? (z1 + row * 256) : (z2 + (row - 4096) * 256);
            float4 v = ((const float4*)src)[lane];
            float ss = v.x * v.x + v.y * v.y + v.z * v.z + v.w * v.w;
#pragma unroll
            for (int m = 32; m > 0; m >>= 1) ss += __shfl_xor(ss, m, 64);
            float sc = 1.0f / fmaxf(sqrtf(ss), 1e-8f);
            uint2 w;
            w.x = f2bf(v.x * sc) | (f2bf(v.y * sc) << 16);
            w.y = f2bf(v.z * sc) | (f2bf(v.w * sc) << 16);
            *(uint2*)(zn + row * 256 + (lane << 2)) = w;
        }
    }
}

// ================= phase 2: FULL-SQUARE sim-exp, uniform streaming pipeline =============
// 512 jobs: job = strip(64) x colRun(8). Each job: 128 rows x 1024 cols = 16 tiles of
// 64 cols = 32 K-halves in one steady double-buffered pipeline. A (wave's 64 rows x
// K=256) lives in registers for the whole job; B halves (16 KB) stream through LDS via
// global_load_lds, prefetched one half ahead so every barrier's vmcnt drain waits on
// loads that are one full compute phase (~1.2k cyc MFMA) old. Row sums accumulate in
// registers; ONE atomic flush per job at the very end (no in-loop atomics anywhere).
// Diagonal needs no masking here: phase 3 subtracts e^{sim_ii}.
__device__ __forceinline__ void phase2(const unsigned short* __restrict__ zn,
                                       float* __restrict__ S,
                                       unsigned short* __restrict__ Bs) {
    const int tid = threadIdx.x, lane = tid & 63, wave = tid >> 6;
    const int q = lane >> 4, n16 = lane & 15;
    const int wr = wave >> 1, wc = wave & 1;
    const int G = gridDim.x;

    // stage one 16KB half: 64 cols x 128 k-elems, chunk-swizzled (slot = src ^ (c&15))
    auto stage = [&](int colBase, int h, int buf) {
        unsigned short* base = Bs + (buf << 13);
#pragma unroll
        for (int p = 0; p < 4; ++p) {
            int s16 = (p << 8) + tid;               // dest 16B slot 0..1023
            int c   = s16 >> 4;                     // col 0..63
            int k8  = (s16 & 15) ^ (c & 15);        // source chunk within half
            GLOADLDS16(zn + ((colBase + c) << 8) + (h << 7) + (k8 << 3),
                       base + (s16 << 3));
        }
    };

    for (int job = blockIdx.x; job < 512; job += G) {
        const int rowBase = (job >> 3) << 7;        // strip * 128
        const int colRun  = (job & 7) << 10;        // run * 1024

        // A: wave's 64 rows x K=256 in registers (128 VGPRs)
        bf16x8 a[4][8];
#pragma unroll
        for (int rt = 0; rt < 4; ++rt)
#pragma unroll
            for (int ks = 0; ks < 8; ++ks)
                a[rt][ks] = *(const bf16x8*)(zn
                    + ((rowBase + (wr << 6) + (rt << 4) + n16) << 8)
                    + (ks << 5) + (q << 3));

        float rs[4][4];
#pragma unroll
        for (int i = 0; i < 4; ++i)
#pragma unroll
            for (int j = 0; j < 4; ++j) rs[i][j] = 0.f;

        stage(colRun, 0, 0);
        int buf = 0;

        for (int tile = 0; tile < 16; ++tile) {
            const int colBase = colRun + (tile << 6);
            f32x4 acc[4][2];
#pragma unroll
            for (int rt = 0; rt < 4; ++rt)
#pragma unroll
                for (int ct = 0; ct < 2; ++ct) acc[rt][ct] = (f32x4){0.f, 0.f, 0.f, 0.f};

#pragma unroll
            for (int h = 0; h < 2; ++h) {
                __syncthreads();                    // current buf staged (loads are old)
                int m = (tile << 1) + h + 1;        // next half index
                if (m < 32) stage(colRun + ((m >> 1) << 6), m & 1, buf ^ 1);

                const unsigned short* bb = Bs + (buf << 13);
#pragma unroll
                for (int ksl = 0; ksl < 4; ++ksl) {
                    bf16x8 bf[2];
#pragma unroll
                    for (int ct = 0; ct < 2; ++ct) {
                        int c  = (wc << 5) + (ct << 4) + n16;
                        int k8 = ((ksl << 2) | q) ^ n16;
                        bf[ct] = *(const bf16x8*)(bb + (((c << 4) | k8) << 3));
                    }
#pragma unroll
                    for (int rt = 0; rt < 4; ++rt)
#pragma unroll
                        for (int ct = 0; ct < 2; ++ct)
                            acc[rt][ct] = __builtin_amdgcn_mfma_f32_16x16x32_bf16(
                                a[rt][(h << 2) + ksl], bf[ct], acc[rt][ct], 0, 0, 0);
                }
                buf ^= 1;
            }

            // epilogue: rowsum += exp(2*dot) — registers only, no branches
#pragma unroll
            for (int rt = 0; rt < 4; ++rt)
#pragma unroll
                for (int ct = 0; ct < 2; ++ct)
#pragma unroll
                    for (int r = 0; r < 4; ++r)
                        rs[rt][r] += __builtin_amdgcn_exp2f(acc[rt][ct][r] * TWO_LOG2E);
        }

        // flush row sums once per job (C/D layout: col=n16, row=q*4+r)
        const int base = rowBase + (wr << 6) + (q << 2);
#pragma unroll
        for (int rt = 0; rt < 4; ++rt)
#pragma unroll
            for (int r = 0; r < 4; ++r) {
                float s = rs[rt][r];
                s += __shfl_xor(s, 1, 64);
                s += __shfl_xor(s, 2, 64);
                s += __shfl_xor(s, 4, 64);
                s += __shfl_xor(s, 8, 64);
                if (n16 == 0) atomicAdd(&S[base + (rt << 4) + r], s);
            }
    }
}

// ================= phase 3: loss = mean( log(S_i - e^{sim_ii}) - sim_{i,tar} ) ==========
__device__ __forceinline__ void phase3(const unsigned short* __restrict__ zn,
                                       const float* __restrict__ S,
                                       float* __restrict__ out,
                                       float* __restrict__ vals) {
    const int tid = threadIdx.x, lane = tid & 63, wave = tid >> 6;
    const int q = lane >> 4, n16 = lane & 15;
    const int rib = (wave << 2) + q;                // 0..15 rows per group
    for (int grp = blockIdx.x; grp < 512; grp += gridDim.x) {
        int row = (grp << 4) + rib;
        int tar = (row + 4096) & 8191;
        float drr = 0.f, drt = 0.f;
#pragma unroll
        for (int i = 0; i < 4; ++i) {
            int k = (i << 6) + (n16 << 2);
            uint2 ur = *(const uint2*)(zn + (row << 8) + k);
            uint2 ut = *(const uint2*)(zn + (tar << 8) + k);
            float a0 = __uint_as_float(ur.x << 16),  a1 = __uint_as_float(ur.x & 0xFFFF0000u);
            float a2 = __uint_as_float(ur.y << 16),  a3 = __uint_as_float(ur.y & 0xFFFF0000u);
            float b0 = __uint_as_float(ut.x << 16),  b1 = __uint_as_float(ut.x & 0xFFFF0000u);
            float b2 = __uint_as_float(ut.y << 16),  b3 = __uint_as_float(ut.y & 0xFFFF0000u);
            drr += a0 * a0 + a1 * a1 + a2 * a2 + a3 * a3;
            drt += a0 * b0 + a1 * b1 + a2 * b2 + a3 * b3;
        }
#pragma unroll
        for (int m = 1; m <= 8; m <<= 1) {
            drr += __shfl_xor(drr, m, 64);
            drt += __shfl_xor(drt, m, 64);
        }
        __syncthreads();
        if (n16 == 0) {
            float Sv = S[row] - __builtin_amdgcn_exp2f(drr * TWO_LOG2E);  // drop diagonal
            vals[rib] = 0.693147180559945f * __builtin_amdgcn_logf(Sv) - 2.0f * drt;
        }
        __syncthreads();
        if (tid == 0) {
            float s = 0.f;
#pragma unroll
            for (int i = 0; i < 16; ++i) s += vals[i];
            atomicAdd(out, s * (1.0f / 8192.0f));
        }
    }
}

// ================= kernels ==============================================================
// (256,1): full 512-reg budget/wave — a[4][8]=128 VGPRs + working set fits w/o spill.
__global__ void __launch_bounds__(256, 1) ntxent_fused(
    const float* __restrict__ z1, const float* __restrict__ z2,
    unsigned short* __restrict__ zn, float* __restrict__ S, float* __restrict__ out)
{
    __shared__ __align__(16) unsigned short Bs[2][8192];   // 2 x 16 KB
    phase1(z1, z2, zn, S, out);
    cg::this_grid().sync();
    phase2(zn, S, &Bs[0][0]);
    cg::this_grid().sync();
    phase3(zn, S, out, (float*)&Bs[0][0]);
}

__global__ void __launch_bounds__(256, 2) norm_k(
    const float* __restrict__ z1, const float* __restrict__ z2,
    unsigned short* __restrict__ zn, float* __restrict__ S, float* __restrict__ out)
{ phase1(z1, z2, zn, S, out); }

__global__ void __launch_bounds__(256, 1) simexp_k(
    const unsigned short* __restrict__ zn, float* __restrict__ S)
{
    __shared__ __align__(16) unsigned short Bs[2][8192];
    phase2(zn, S, &Bs[0][0]);
}

__global__ void __launch_bounds__(256, 2) finish_k(
    const unsigned short* __restrict__ zn, const float* __restrict__ S,
    float* __restrict__ out)
{
    __shared__ float vals[16];
    phase3(zn, S, out, vals);
}

extern "C" void kernel_launch(void* const* d_in, const int* in_sizes, int n_in,
                              void* d_out, int out_size, void* d_ws, size_t ws_size,
                              hipStream_t stream)
{
    const float* z1 = (const float*)d_in[0];
    const float* z2 = (const float*)d_in[1];
    unsigned short* zn = (unsigned short*)d_ws;                              // 4 MB
    float* S = (float*)((char*)d_ws + 8192 * 256 * sizeof(unsigned short));  // 32 KB
    float* out = (float*)d_out;

    // Host-only queries (graph-capture safe): pick cooperative grid size or fall back.
    int dev = 0;
    hipGetDevice(&dev);
    int coopOK = 0;
    hipDeviceGetAttribute(&coopOK, hipDeviceAttributeCooperativeLaunch, dev);
    int cus = 0;
    hipDeviceGetAttribute(&cus, hipDeviceAttributeMultiprocessorCount, dev);
    int maxB = 0;
    hipOccupancyMaxActiveBlocksPerMultiprocessor(&maxB, ntxent_fused, 256, 0);

    long long cap = (long long)maxB * (long long)cus;
    int G = (cap >= 512) ? 512 : (int)cap;

    if (coopOK && G >= 128) {
        void* args[] = {(void*)&z1, (void*)&z2, (void*)&zn, (void*)&S, (void*)&out};
        hipError_t err = hipLaunchCooperativeKernel(ntxent_fused, dim3(G), dim3(256),
                                                    args, 0, stream);
        if (err == hipSuccess) return;
    }
    // Fallback: same phases as separate (non-cooperative) kernels.
    norm_k<<<512, 256, 0, stream>>>(z1, z2, zn, S, out);
    simexp_k<<<512, 256, 0, stream>>>(zn, S);
    finish_k<<<512, 256, 0, stream>>>(zn, S, out);
}